// Round 14
// baseline (199.141 us; speedup 1.0000x reference)
//
#include <hip/hip_runtime.h>
#include <stdint.h>

typedef unsigned short u16;
typedef unsigned int   u32;
typedef unsigned long long u64;
typedef __attribute__((ext_vector_type(8)))  short short8;   // 8 x bf16 fragment
typedef __attribute__((ext_vector_type(4)))  float f32x4;
typedef __attribute__((ext_vector_type(16))) float f32x16;   // 32x32 MFMA accumulator
typedef __attribute__((ext_vector_type(4)))  unsigned int u32x4;

// ---------- helpers ----------
__device__ __forceinline__ u16 f2bf(float f) {          // RNE f32 -> bf16
  u32 u = __builtin_bit_cast(u32, f);
  u32 r = u + 0x7FFFu + ((u >> 16) & 1u);
  return (u16)(r >> 16);
}

__device__ __forceinline__ u32 cvtpk(float a, float b) { // 2xf32 -> packed bf16
  u32 r;
  asm("v_cvt_pk_bf16_f32 %0, %1, %2" : "=v"(r) : "v"(a), "v"(b));
  return r;
}

// async global->LDS, 16B per lane (dest must be wave-uniform base + lane*16)
__device__ __forceinline__ void gload_lds16(const void* g, void* l) {
  __builtin_amdgcn_global_load_lds(
      (__attribute__((address_space(1))) void*)(uintptr_t)g,
      (__attribute__((address_space(3))) void*)(u32)(uintptr_t)l,
      16, 0, 0);
}

#define SB() __builtin_amdgcn_sched_barrier(0)

// ---------- fused weight casts: grid.y selects which 512x512 matrix ----------
__global__ void cast4_kernel(const float* __restrict__ s0, const float* __restrict__ s1,
                             const float* __restrict__ s2, const float* __restrict__ s3,
                             u16* __restrict__ d0, u16* __restrict__ d1,
                             u16* __restrict__ d2, u16* __restrict__ d3, int n8) {
  const int sel = blockIdx.y;
  const float* src = sel == 0 ? s0 : sel == 1 ? s1 : sel == 2 ? s2 : s3;
  u16* dst = sel == 0 ? d0 : sel == 1 ? d1 : sel == 2 ? d2 : d3;
  int i = blockIdx.x * blockDim.x + threadIdx.x;
  if (i >= n8) return;
  const float4* s4 = (const float4*)src;
  float4 x = s4[2 * (size_t)i];
  float4 y = s4[2 * (size_t)i + 1];
  u32x4 r;
  r.x = cvtpk(x.x, x.y); r.y = cvtpk(x.z, x.w);
  r.z = cvtpk(y.x, y.y); r.w = cvtpk(y.z, y.w);
  *(u32x4*)(dst + 8 * (size_t)i) = r;
}

// ---------- pack {q_seq, c_bits} per position ----------
__global__ void pack_kernel(const int* __restrict__ q_seq, const int* __restrict__ c_seq,
                            int2* __restrict__ meta, int n) {
  int i = blockIdx.x * blockDim.x + threadIdx.x;
  if (i >= n) return;
  u32 bits = 0;
#pragma unroll
  for (int j = 0; j < 32; ++j)
    bits |= (c_seq[(size_t)i * 32 + j] != 0) ? (1u << j) : 0u;
  meta[i] = make_int2(q_seq[i], (int)bits);
}

// ---------- mask precompute: 2-bit m per (b, ktile32, q), tri included ----------
__global__ __launch_bounds__(256) void mask_kernel(const int2* __restrict__ meta,
                                                   u64* __restrict__ maskw) {
  const int qc = blockIdx.x, kt = blockIdx.y, b = blockIdx.z;
  const int t = threadIdx.x;
  const int q = qc * 256 + t;
  __shared__ int2 colm[32];
  if (t < 32) colm[t] = meta[b * 1024 + kt * 32 + t];
  __syncthreads();
  const int2 qm = meta[b * 1024 + q];
  const int rs = qm.x; const u32 rb = (u32)qm.y;
  u64 w = 0;
#pragma unroll
  for (int j = 0; j < 32; ++j) {
    const int2 cm = colm[j];
    const int kj = kt * 32 + j;
    u32 m = 0;
    if (kj < q) m = 1u + (rs == cm.x ? 1u : 0u) + (((rb & (u32)cm.y) != 0u) ? 1u : 0u);
    w |= (u64)m << (2 * j);
  }
  maskw[((size_t)b * 32 + kt) * 1024 + q] = w;
}

// ---------- QKV projection: A-RESIDENT 64-row stripe, B streamed ----------
// Traffic fix (R6..R13 all ~73-89us at 400MB L3 A-traffic): each block owns a
// 64-row A-stripe, cvt f32->bf16 ONCE into swizzled 64KB LDS (A L3 traffic
// 400->100MB); B (L2-resident 0.5MB weights) streams via gload_lds dbuf
// 2x8KB, one barrier/step. 80KB LDS -> 2 blocks/CU. 64 steps = 8 nbi x 8 kt.
//  which 0 (Q): out [b][h][s][64]
//  which 1 (K): tiled [b][h][s/32][d/8][s&31][d&7]
//  which 2 (V): tiled [b][h][s/8][d][s&7]
__global__ __launch_bounds__(256, 2) void gemm_qkv(const float* __restrict__ qf,
                                                   const float* __restrict__ kf,
                                                   const float* __restrict__ vf,
                                                   const u16* __restrict__ Wvb,
                                                   const u16* __restrict__ Wkb,
                                                   const u16* __restrict__ Wqb,
                                                   const float* __restrict__ bv,
                                                   const float* __restrict__ bk,
                                                   const float* __restrict__ bq,
                                                   u16* __restrict__ qhb,
                                                   u16* __restrict__ khb,
                                                   u16* __restrict__ vTb,
                                                   float kscale) {
  __shared__ __align__(16) u16 Alds[64 * 512];   // 64KB resident A (bf16, swizzled)
  __shared__ __align__(16) u16 Bb[2][64 * 64];   // 2 x 8KB B tiles
  const int t    = threadIdx.x;
  const int lane = t & 63;
  const int wid  = t >> 6;
  const int g    = lane >> 4, l15 = lane & 15;
  const int mb   = blockIdx.x;
  const int which = mb >> 8;                     // 0:q 1:k 2:v (256 stripes each)
  const float* Ax   = which == 0 ? qf : which == 1 ? kf : vf;
  const u16*   W    = which == 0 ? Wvb : which == 1 ? Wkb : Wqb;  // ref shuffle
  const float* bias = which == 0 ? bv : which == 1 ? bk : bq;
  const float scale = which == 1 ? kscale : 1.0f;
  u16* outb = which == 0 ? qhb : which == 1 ? khb : vTb;
  const int mloc = (mb & 255) << 6;              // 64-row stripe base

  const int arow = wid * 16 + l15;               // this lane's A row (MFMA frag)
  const int ar7  = arow & 7;

  // ---- Phase 1: A stripe f32 -> bf16, swizzled LDS, read ONCE from L3 ----
  // unit u = j*256+t: row = u>>6 (wave-uniform), slot = u&63 (=lane)
#pragma unroll
  for (int j = 0; j < 16; ++j) {
    const int u = j * 256 + t;
    const int row = u >> 6;
    const int slot = u & 63;
    const float* src = Ax + (size_t)(mloc + row) * 512 + slot * 8;
    const float4 x = *(const float4*)src;
    const float4 y = *(const float4*)(src + 4);
    u32x4 r;
    r.x = cvtpk(x.x, x.y); r.y = cvtpk(x.z, x.w);
    r.z = cvtpk(y.x, y.y); r.w = cvtpk(y.z, y.w);
    *(u32x4*)(&Alds[row * 512 + ((slot ^ (row & 7)) << 3)]) = r;
  }

#define STAGE_B(nb, kt, buf)                                                  \
  { _Pragma("unroll")                                                         \
    for (int i2 = 0; i2 < 2; ++i2) {                                          \
      const int u2 = i2 * 256 + t;                                            \
      const int bc = u2 >> 3, bs = u2 & 7;                                    \
      gload_lds16(W + (size_t)((nb) * 64 + bc) * 512 + (kt) * 64             \
                    + ((bs ^ (bc & 7)) << 3),                                 \
                  &Bb[buf][u2 * 8]);                                          \
    } }

  STAGE_B(0, 0, 0);
  __syncthreads();                                // A writes + B(0) landed

  f32x4 acc[4];
#pragma unroll
  for (int j = 0; j < 4; ++j) acc[j] = f32x4{0.f, 0.f, 0.f, 0.f};

  for (int s = 0; s < 64; ++s) {
    const int cur = s & 1;
    const int sn = (s + 1) & 63;
    STAGE_B(sn >> 3, sn & 7, cur ^ 1);            // 2 vmem for next step
    SB();
    const int kt = s & 7;
#pragma unroll
    for (int kk = 0; kk < 2; ++kk) {
      const int sA = kt * 8 + kk * 4 + g;
      const short8 a = *(const short8*)(&Alds[arow * 512 + ((sA ^ ar7) << 3)]);
#pragma unroll
      for (int ni = 0; ni < 4; ++ni) {
        const int bcol = ni * 16 + l15;
        const int sBp = ((kk * 4 + g) ^ (bcol & 7)) << 3;
        const short8 b = *(const short8*)(&Bb[cur][bcol * 64 + sBp]);
        acc[ni] = __builtin_amdgcn_mfma_f32_16x16x32_bf16(a, b, acc[ni], 0, 0, 0);
      }
    }
    if (kt == 7) {
      const int nbi = s >> 3;
#pragma unroll
      for (int ni = 0; ni < 4; ++ni) {
        const int col = nbi * 64 + ni * 16 + l15;   // 0..511 within this third
        const float bz = bias[col];
#pragma unroll
        for (int r = 0; r < 4; ++r) {
          const int row = mloc + wid * 16 + g * 4 + r;
          const u16 val = f2bf((acc[ni][r] + bz) * scale);
          const size_t base = ((size_t)(row >> 10) * 8 + (col >> 6)) * 65536;
          const int ss = row & 1023, d = col & 63;
          if (which == 0) {
            outb[base + (size_t)ss * 64 + d] = val;
          } else if (which == 1) {
            outb[base + (ss >> 5) * 2048 + (d >> 3) * 256 + (ss & 31) * 8 + (d & 7)] = val;
          } else {
            outb[base + (ss >> 3) * 512 + d * 8 + (ss & 7)] = val;
          }
          acc[ni][r] = 0.f;
        }
      }
    }
    SB();
    asm volatile("s_waitcnt vmcnt(0)" ::: "memory");  // covered by 10 ds_read + 8 MFMA
    __builtin_amdgcn_s_barrier();
    SB();
  }
#undef STAGE_B
}

// ---------- final GEMM: A-RESIDENT 64-row stripe (bf16 via gload_lds) ------
__global__ __launch_bounds__(256, 2) void gemm_out(const u16* __restrict__ A,
                                                   const u16* __restrict__ W,
                                                   const float* __restrict__ bias,
                                                   float* __restrict__ outp) {
  __shared__ __align__(16) u16 Alds[64 * 512];
  __shared__ __align__(16) u16 Bb[2][64 * 64];
  const int t    = threadIdx.x;
  const int lane = t & 63;
  const int wid  = t >> 6;
  const int g    = lane >> 4, l15 = lane & 15;
  const int mloc = blockIdx.x << 6;
  const int arow = wid * 16 + l15;
  const int ar7  = arow & 7;

  // Phase 1: A stripe via gload_lds (already bf16); dest = u*16B (linear,
  // wave-uniform base + lane*16); source pre-swizzled (rule 21)
#pragma unroll
  for (int j = 0; j < 16; ++j) {
    const int u = j * 256 + t;
    const int row = u >> 6;
    const int slot = u & 63;
    gload_lds16(A + (size_t)(mloc + row) * 512 + ((slot ^ (row & 7)) << 3),
                &Alds[u * 8]);
  }

#define STAGE_B(nb, kt, buf)                                                  \
  { _Pragma("unroll")                                                         \
    for (int i2 = 0; i2 < 2; ++i2) {                                          \
      const int u2 = i2 * 256 + t;                                            \
      const int bc = u2 >> 3, bs = u2 & 7;                                    \
      gload_lds16(W + (size_t)((nb) * 64 + bc) * 512 + (kt) * 64             \
                    + ((bs ^ (bc & 7)) << 3),                                 \
                  &Bb[buf][u2 * 8]);                                          \
    } }

  STAGE_B(0, 0, 0);
  __syncthreads();

  f32x4 acc[4];
#pragma unroll
  for (int j = 0; j < 4; ++j) acc[j] = f32x4{0.f, 0.f, 0.f, 0.f};

  for (int s = 0; s < 64; ++s) {
    const int cur = s & 1;
    const int sn = (s + 1) & 63;
    STAGE_B(sn >> 3, sn & 7, cur ^ 1);
    SB();
    const int kt = s & 7;
#pragma unroll
    for (int kk = 0; kk < 2; ++kk) {
      const int sA = kt * 8 + kk * 4 + g;
      const short8 a = *(const short8*)(&Alds[arow * 512 + ((sA ^ ar7) << 3)]);
#pragma unroll
      for (int ni = 0; ni < 4; ++ni) {
        const int bcol = ni * 16 + l15;
        const int sBp = ((kk * 4 + g) ^ (bcol & 7)) << 3;
        const short8 b = *(const short8*)(&Bb[cur][bcol * 64 + sBp]);
        acc[ni] = __builtin_amdgcn_mfma_f32_16x16x32_bf16(a, b, acc[ni], 0, 0, 0);
      }
    }
    if (kt == 7) {
      const int nbi = s >> 3;
#pragma unroll
      for (int ni = 0; ni < 4; ++ni) {
        const int col = nbi * 64 + ni * 16 + l15;
        const float bz = bias[col];
#pragma unroll
        for (int r = 0; r < 4; ++r) {
          const int row = mloc + wid * 16 + g * 4 + r;
          outp[(size_t)row * 512 + col] = acc[ni][r] + bz;
          acc[ni][r] = 0.f;
        }
      }
    }
    SB();
    asm volatile("s_waitcnt vmcnt(0)" ::: "memory");
    __builtin_amdgcn_s_barrier();
    SB();
  }
#undef STAGE_B
}

// ---------- flash attention: wave-pair kv-split + 2-tile ILP (R13) ----------
__global__ __launch_bounds__(256, 2) void attn_kernel(const u16* __restrict__ qh,
                                                      const u16* __restrict__ kh,
                                                      const u16* __restrict__ vT,
                                                      const u64* __restrict__ maskw,
                                                      u16* __restrict__ outc) {
  const int h  = blockIdx.x;
  const int qp = blockIdx.y;
  const int b  = blockIdx.z;
  const int lane = threadIdx.x & 63;
  const int wid  = threadIdx.x >> 6;
  const int pair = wid >> 1, p = wid & 1;
  const int l31 = lane & 31;
  const int hh  = lane >> 5;
  const int hh8 = hh << 3, fourh = hh << 2, eighth = hh << 3;
  const int jt = pair ? (31 - qp) : qp;   // q-tile index 0..31
  const int q0 = jt << 5;
  const int qi = q0 + l31;
  const size_t bh = (size_t)b * 8 + h;
  const u16* Q  = qh + bh * 65536;
  const u16* Kp = kh + bh * 65536;
  const u16* Vt = vT + bh * 65536;
  const u64* mrow = maskw + (size_t)b * 32768 + qi;

  __shared__ float mO[2][32][64];
  __shared__ float mL[2][64];
  __shared__ __align__(16) float Sl[2][32];

  short8 qB[4];
#pragma unroll
  for (int i = 0; i < 4; ++i)
    qB[i] = *(const short8*)(Q + (size_t)qi * 64 + i * 16 + eighth);

  f32x16 O0, O1;
#pragma unroll
  for (int i = 0; i < 16; ++i) { O0[i] = 0.f; O1[i] = 0.f; }
  float lr[4] = {0.f, 0.f, 0.f, 0.f};

  const int nt = jt + 1;

#define LOADK(dst, tt)                                                        \
  { _Pragma("unroll")                                                         \
    for (int i = 0; i < 4; ++i)                                               \
      dst[i] = *(const short8*)(Kp + (tt) * 2048 + ((2 * i + hh) * 32 + l31) * 8); }

#define SOFTMAX(S, wm, pkk)                                                   \
  { const u32 wsh0 = ((u32)(wm)) >> hh8;                                      \
    const u32 wsh1 = ((u32)((wm) >> 32)) >> hh8;                              \
    _Pragma("unroll")                                                         \
    for (int s = 0; s < 4; ++s) {                                             \
      const u32 wsel = (s < 2) ? wsh0 : wsh1;                                 \
      float pv[4];                                                            \
      _Pragma("unroll")                                                       \
      for (int r = 0; r < 4; ++r) {                                           \
        const int m = 4 * s + r;                                              \
        const u32 m2 = (wsel >> (2 * r + 16 * (s & 1))) & 3u;                 \
        float e;                                                              \
        asm("v_exp_f32 %0, %1" : "=v"(e) : "v"((S)[m]));                      \
        const float pp = (m2 != 0u) ? e : 0.f;                                \
        lr[r] += pp;                                                          \
        asm("v_ldexp_f32 %0, %1, %2" : "=v"(pv[r]) : "v"(pp), "v"(m2));       \
      }                                                                       \
      pkk[2 * s]     = cvtpk(pv[0], pv[1]);                                   \
      pkk[2 * s + 1] = cvtpk(pv[2], pv[3]);                                   \
    } }

#define PVSTEP(pkk, tt)                                                       \
  { _Pragma("unroll")                                                         \
    for (int t4 = 0; t4 < 2; ++t4) {                                          \
      u32 a0 = pkk[4 * t4 + 0], b0 = pkk[4 * t4 + 2];                         \
      u32 a1 = pkk[4 * t4 + 1], b1 = pkk[4 * t4 + 3];                         \
      asm("v_permlane32_swap_b32 %0, %1" : "+v"(a0), "+v"(b0));               \
      asm("v_permlane32_swap_b32 %0, %1" : "+v"(a1), "+v"(b1));               \
      u32x4 w; w.x = a0; w.y = a1; w.z = b0; w.w = b1;                        \
      const short8 pa = __builtin_bit_cast(short8, w);                        \
      const short8 v0 = *(const short8*)(Vt + (size_t)((tt) * 4 + t4 * 2 + hh) * 512 + l31 * 8); \
      const short8 v1 = *(const short8*)(Vt + (size_t)((tt) * 4 + t4 * 2 + hh) * 512 + (32 + l31) * 8); \
      O0 = __builtin_amdgcn_mfma_f32_32x32x16_bf16(pa, v0, O0, 0, 0, 0);      \
      O1 = __builtin_amdgcn_mfma_f32_32x32x16_bf16(pa, v1, O1, 0, 0, 0);      \
    } }

  short8 kAa[4], kAb[4];
  LOADK(kAa, p);
  LOADK(kAb, (p + 2));
  u64 wma = mrow[(size_t)p << 10];
  u64 wmb = mrow[(size_t)(p + 2) << 10];

  int t = p;
  while (t < nt) {
    const bool two = (t + 2) < nt;

    f32x16 Sa;
#pragma unroll
    for (int i = 0; i < 16; ++i) Sa[i] = 0.f;
#pragma unroll
    for (int i = 0; i < 4; ++i)
      Sa = __builtin_amdgcn_mfma_f32_32x32x16_bf16(kAa[i], qB[i], Sa, 0, 0, 0);
    f32x16 Sb;
#pragma unroll
    for (int i = 0; i < 16; ++i) Sb[i] = 0.f;
    if (two) {
#pragma unroll
      for (int i = 0; i < 4; ++i)
        Sb = __builtin_amdgcn_mfma_f32_32x32x16_bf16(kAb[i], qB[i], Sb, 0, 0, 0);
    }

    const int tn = t + (two ? 4 : 2);
    u64 wman = 0, wmbn = 0;
    if (tn < nt) {
      LOADK(kAa, tn);
      wman = mrow[(size_t)tn << 10];
      if (tn + 2 < nt) {
        LOADK(kAb, (tn + 2));
        wmbn = mrow[(size_t)(tn + 2) << 10];
      }
    }

    u32 pka[8], pkb[8];
    SOFTMAX(Sa, wma, pka);
    if (two) SOFTMAX(Sb, wmb, pkb);

    PVSTEP(pka, t);
    if (two) PVSTEP(pkb, (t + 2));

    wma = wman; wmb = wmbn;
    t = tn;
  }

#undef LOADK
#undef SOFTMAX
#undef PVSTEP

  float lrun = (lr[0] + lr[1]) + (lr[2] + lr[3]);

  if (p == 1) {
#pragma unroll
    for (int r = 0; r < 16; ++r) {
      mO[pair][r][lane]      = O0[r];
      mO[pair][16 + r][lane] = O1[r];
    }
    mL[pair][lane] = lrun;
  }
  __syncthreads();
  if (p == 0) {
#pragma unroll
    for (int r = 0; r < 16; ++r) {
      O0[r] += mO[pair][r][lane];
      O1[r] += mO[pair][16 + r][lane];
    }
    lrun += mL[pair][lane];

    const float ssum = lrun + __shfl_xor(lrun, 32);
    if (lane < 32) Sl[pair][l31] = (ssum > 0.f) ? 0.25f / ssum : 0.f;
    __builtin_amdgcn_sched_barrier(0);
    asm volatile("s_waitcnt lgkmcnt(0)" ::: "memory");
    __builtin_amdgcn_sched_barrier(0);
#pragma unroll
    for (int t2 = 0; t2 < 4; ++t2) {
      const float4 inv4 = *(const float4*)&Sl[pair][8 * t2 + fourh];
#pragma unroll
      for (int r = 0; r < 4; ++r) {
        const int m = 4 * t2 + r;
        const float iv = (r == 0) ? inv4.x : (r == 1) ? inv4.y : (r == 2) ? inv4.z : inv4.w;
        const int qrow = q0 + 8 * t2 + fourh + r;
        u16* op = outc + ((size_t)b * 1024 + qrow) * 512 + h * 64;
        op[l31]      = f2bf(O0[m] * iv);
        op[32 + l31] = f2bf(O1[m] * iv);
      }
    }
  }
}

// ---------- launch ----------
extern "C" void kernel_launch(void* const* d_in, const int* in_sizes, int n_in,
                              void* d_out, int out_size, void* d_ws, size_t ws_size,
                              hipStream_t stream) {
  (void)in_sizes; (void)n_in; (void)out_size; (void)ws_size;
  const float* q    = (const float*)d_in[0];
  const float* k    = (const float*)d_in[1];
  const float* v    = (const float*)d_in[2];
  const int*  q_seq = (const int*)d_in[3];
  const int*  c_seq = (const int*)d_in[4];
  const float* Wq   = (const float*)d_in[5];
  const float* bq   = (const float*)d_in[6];
  const float* Wk   = (const float*)d_in[7];
  const float* bk   = (const float*)d_in[8];
  const float* Wv   = (const float*)d_in[9];
  const float* bv   = (const float*)d_in[10];
  const float* Wo   = (const float*)d_in[11];
  const float* bo   = (const float*)d_in[12];
  float* out = (float*)d_out;

  char* ws = (char*)d_ws;
  const size_t SZH = 16ull * 8 * 1024 * 64 * 2;   // 16.78 MB per [B][H][...] bf16
  u16* qhb   = (u16*)(ws + 0 * SZH);
  u16* khb   = (u16*)(ws + 1 * SZH);
  u16* vTb   = (u16*)(ws + 2 * SZH);
  u16* attnc = (u16*)(ws + 3 * SZH);
  u16* Wvb = (u16*)(ws + 4 * SZH + 0 * 524288);
  u16* Wkb = (u16*)(ws + 4 * SZH + 1 * 524288);
  u16* Wqb = (u16*)(ws + 4 * SZH + 2 * 524288);
  u16* Wob = (u16*)(ws + 4 * SZH + 3 * 524288);
  int2* meta  = (int2*)(ws + 4 * SZH + 4 * 524288);
  u64* maskw  = (u64*)(ws + 4 * SZH + 4 * 524288 + 131072);

  const int n8w = 512 * 512 / 8;
  cast4_kernel<<<dim3(n8w / 256, 4), 256, 0, stream>>>(Wv, Wk, Wq, Wo,
                                                       Wvb, Wkb, Wqb, Wob, n8w);
  pack_kernel<<<64, 256, 0, stream>>>(q_seq, c_seq, meta, 16384);
  mask_kernel<<<dim3(4, 32, 16), 256, 0, stream>>>(meta, maskw);

  const float KSCALE = 0.18033688011112042f;   // log2(e)/8 -> softmax exp is 2^s
  gemm_qkv<<<dim3(768), 256, 0, stream>>>(q, k, v, Wvb, Wkb, Wqb,
                                          bv, bk, bq, qhb, khb, vTb, KSCALE);
  attn_kernel<<<dim3(8, 16, 16), 256, 0, stream>>>(qhb, khb, vTb, maskw, attnc);
  gemm_out<<<dim3(256), 256, 0, stream>>>(attnc, Wob, bo, out);
}

// Round 15
// 157.380 us; speedup vs baseline: 1.2653x; 1.2653x over previous
//
#include <hip/hip_runtime.h>
#include <stdint.h>

typedef unsigned short u16;
typedef unsigned int   u32;
typedef unsigned long long u64;
typedef __attribute__((ext_vector_type(8)))  short short8;   // 8 x bf16 fragment
typedef __attribute__((ext_vector_type(4)))  float f32x4;
typedef __attribute__((ext_vector_type(16))) float f32x16;   // 32x32 MFMA accumulator
typedef __attribute__((ext_vector_type(4)))  unsigned int u32x4;

// ---------- helpers ----------
__device__ __forceinline__ u16 f2bf(float f) {          // RNE f32 -> bf16
  u32 u = __builtin_bit_cast(u32, f);
  u32 r = u + 0x7FFFu + ((u >> 16) & 1u);
  return (u16)(r >> 16);
}

__device__ __forceinline__ u32 cvtpk(float a, float b) { // 2xf32 -> packed bf16
  u32 r;
  asm("v_cvt_pk_bf16_f32 %0, %1, %2" : "=v"(r) : "v"(a), "v"(b));
  return r;
}

// async global->LDS, 16B per lane (dest must be wave-uniform base + lane*16)
__device__ __forceinline__ void gload_lds16(const void* g, void* l) {
  __builtin_amdgcn_global_load_lds(
      (__attribute__((address_space(1))) void*)(uintptr_t)g,
      (__attribute__((address_space(3))) void*)(u32)(uintptr_t)l,
      16, 0, 0);
}

#define SB() __builtin_amdgcn_sched_barrier(0)

// ---------- fused weight casts: grid.y selects which 512x512 matrix ----------
__global__ void cast4_kernel(const float* __restrict__ s0, const float* __restrict__ s1,
                             const float* __restrict__ s2, const float* __restrict__ s3,
                             u16* __restrict__ d0, u16* __restrict__ d1,
                             u16* __restrict__ d2, u16* __restrict__ d3, int n8) {
  const int sel = blockIdx.y;
  const float* src = sel == 0 ? s0 : sel == 1 ? s1 : sel == 2 ? s2 : s3;
  u16* dst = sel == 0 ? d0 : sel == 1 ? d1 : sel == 2 ? d2 : d3;
  int i = blockIdx.x * blockDim.x + threadIdx.x;
  if (i >= n8) return;
  const float4* s4 = (const float4*)src;
  float4 x = s4[2 * (size_t)i];
  float4 y = s4[2 * (size_t)i + 1];
  u32x4 r;
  r.x = cvtpk(x.x, x.y); r.y = cvtpk(x.z, x.w);
  r.z = cvtpk(y.x, y.y); r.w = cvtpk(y.z, y.w);
  *(u32x4*)(dst + 8 * (size_t)i) = r;
}

// ---------- pack {q_seq, c_bits} per position ----------
__global__ void pack_kernel(const int* __restrict__ q_seq, const int* __restrict__ c_seq,
                            int2* __restrict__ meta, int n) {
  int i = blockIdx.x * blockDim.x + threadIdx.x;
  if (i >= n) return;
  u32 bits = 0;
#pragma unroll
  for (int j = 0; j < 32; ++j)
    bits |= (c_seq[(size_t)i * 32 + j] != 0) ? (1u << j) : 0u;
  meta[i] = make_int2(q_seq[i], (int)bits);
}

// ---------- mask precompute: 2-bit m per (b, ktile32, q), tri included ----------
__global__ __launch_bounds__(256) void mask_kernel(const int2* __restrict__ meta,
                                                   u64* __restrict__ maskw) {
  const int qc = blockIdx.x, kt = blockIdx.y, b = blockIdx.z;
  const int t = threadIdx.x;
  const int q = qc * 256 + t;
  __shared__ int2 colm[32];
  if (t < 32) colm[t] = meta[b * 1024 + kt * 32 + t];
  __syncthreads();
  const int2 qm = meta[b * 1024 + q];
  const int rs = qm.x; const u32 rb = (u32)qm.y;
  u64 w = 0;
#pragma unroll
  for (int j = 0; j < 32; ++j) {
    const int2 cm = colm[j];
    const int kj = kt * 32 + j;
    u32 m = 0;
    if (kj < q) m = 1u + (rs == cm.x ? 1u : 0u) + (((rb & (u32)cm.y) != 0u) ? 1u : 0u);
    w |= (u64)m << (2 * j);
  }
  maskw[((size_t)b * 32 + kt) * 1024 + q] = w;
}

// ---------- QKV projection: R6-exact inner loop, 128x256 tile (2-nbi) ------
// ONLY change vs the 73us R6 structure: each block covers 256 output cols
// (nbi in {0,1}), halving A re-reads (4x -> 2x; ~400 -> ~200 MB L2/L3
// traffic). Same barriers, same vmcnt(8) accounting (B=8 gloads now; after
// A-prefetch outstanding = B8+A8=16 -> vmcnt(8) drains exactly B).
// Stacked M: which = mb>>7 selects input/weight/bias/output.
//  which 0 (Q): out [b][h][s][64]
//  which 1 (K): tiled [b][h][s/32][d/8][s&31][d&7]
//  which 2 (V): tiled [b][h][s/8][d][s&7]
__global__ __launch_bounds__(256) void gemm_qkv(const float* __restrict__ qf,
                                                const float* __restrict__ kf,
                                                const float* __restrict__ vf,
                                                const u16* __restrict__ Wcat,
                                                const float* __restrict__ bv,
                                                const float* __restrict__ bk,
                                                const float* __restrict__ bq,
                                                u16* __restrict__ qhb,
                                                u16* __restrict__ khb,
                                                u16* __restrict__ vTb,
                                                float kscale) {
  const int K = 512;
  __shared__ __align__(16) u16 As[128 * 64];      // 16 KB
  __shared__ __align__(16) u16 Bs[256 * 64];      // 32 KB
  const int t    = threadIdx.x;
  const int lane = t & 63;
  const int wid  = t >> 6;
  const int g    = lane >> 4, l15 = lane & 15;
  const int wm   = wid >> 1, wn = wid & 1;        // 2x2 waves: 64 rows x 128 cols each
  const int wrk  = (blockIdx.x & 7) * 96 + (blockIdx.x >> 3);  // XCD-chunked, 768
  const int mb   = wrk >> 1, nbi = wrk & 1;
  const int which = mb >> 7;                      // 0:q 1:k 2:v
  const float* Ax   = which == 0 ? qf : which == 1 ? kf : vf;
  const float* bias = which == 0 ? bv : which == 1 ? bk : bq;  // ref weight shuffle
  const float scale = which == 1 ? kscale : 1.0f;
  u16* outb = which == 0 ? qhb : which == 1 ? khb : vTb;
  const int mloc = (mb & 127) << 7;               // row base within this input
  const int n0   = nbi << 8;                      // col base (0 or 256)
  const u16* W   = Wcat + (size_t)which * 512 * 512;

  const int srow = t >> 3;
  const int scol = (((t & 7) ^ (srow & 7)) << 3); // pre-swizzled source slot
  const int dcol = ((t & 7) << 3);                // linear LDS dest slot
  const int rsw  = l15 & 7;                       // read-side swizzle key

  f32x4 acc[4][8];
#pragma unroll
  for (int i = 0; i < 4; ++i)
#pragma unroll
    for (int j = 0; j < 8; ++j) acc[i][j] = f32x4{0.f, 0.f, 0.f, 0.f};

  // prologue: A(k0=0) into regs (8 vmem, oldest)
  float4 ax[4], ay[4];
#pragma unroll
  for (int i = 0; i < 4; ++i) {
    const float* src = Ax + (size_t)(mloc + 32 * i + srow) * K + scol;
    ax[i] = *(const float4*)src;
    ay[i] = *(const float4*)(src + 4);
  }

  for (int k0 = 0; k0 < K; k0 += 64) {
    SB();
    __builtin_amdgcn_s_barrier();      // prev-iter LDS reads done
    SB();
    // B stage (8 gload_lds: 256 rows, linear dest, pre-swizzled source)
#pragma unroll
    for (int i = 0; i < 8; ++i)
      gload_lds16(W + (size_t)(n0 + i * 32 + srow) * K + k0 + scol,
                  Bs + i * 2048 + t * 8);
    // A cvt (regs loaded last iter; auto vmcnt drains the 8 A) -> ds_write
#pragma unroll
    for (int i = 0; i < 4; ++i) {
      u32x4 r;
      r.x = cvtpk(ax[i].x, ax[i].y); r.y = cvtpk(ax[i].z, ax[i].w);
      r.z = cvtpk(ay[i].x, ay[i].y); r.w = cvtpk(ay[i].z, ay[i].w);
      *(u32x4*)(As + (32 * i + srow) * 64 + dcol) = r;
    }
    SB();
    // A prefetch next K-step (wrap keeps 8 loads/iter -> vmcnt invariant)
    const int kn = (k0 + 64) & (K - 1);
#pragma unroll
    for (int i = 0; i < 4; ++i) {
      const float* src = Ax + (size_t)(mloc + 32 * i + srow) * K + kn + scol;
      ax[i] = *(const float4*)src;
      ay[i] = *(const float4*)(src + 4);
    }
    SB();
    asm volatile("s_waitcnt vmcnt(8) lgkmcnt(0)" ::: "memory");  // B+dsW done; A flies
    __builtin_amdgcn_s_barrier();
    SB();
#pragma unroll
    for (int kk = 0; kk < 2; ++kk) {
      short8 a[4], b[8];
#pragma unroll
      for (int mi = 0; mi < 4; ++mi)
        a[mi] = *(const short8*)(As + (wm * 64 + mi * 16 + l15) * 64
                                 + (((kk * 4 + g) ^ rsw) << 3));
#pragma unroll
      for (int ni = 0; ni < 8; ++ni)
        b[ni] = *(const short8*)(Bs + (wn * 128 + ni * 16 + l15) * 64
                                 + (((kk * 4 + g) ^ rsw) << 3));
#pragma unroll
      for (int mi = 0; mi < 4; ++mi)
#pragma unroll
        for (int ni = 0; ni < 8; ++ni)
          acc[mi][ni] = __builtin_amdgcn_mfma_f32_16x16x32_bf16(a[mi], b[ni], acc[mi][ni], 0, 0, 0);
    }
  }
  asm volatile("s_waitcnt vmcnt(0)" ::: "memory");   // drain dead last prefetch

#pragma unroll
  for (int ni = 0; ni < 8; ++ni) {
    const int col = n0 + wn * 128 + ni * 16 + l15;   // 0..511 within this third
    const float bz = bias[col];
#pragma unroll
    for (int mi = 0; mi < 4; ++mi) {
#pragma unroll
      for (int r = 0; r < 4; ++r) {
        const int row = mloc + wm * 64 + mi * 16 + g * 4 + r;
        const u16 val = f2bf((acc[mi][ni][r] + bz) * scale);
        const size_t base = ((size_t)(row >> 10) * 8 + (col >> 6)) * 65536;
        const int s = row & 1023, d = col & 63;
        if (which == 0) {
          outb[base + (size_t)s * 64 + d] = val;
        } else if (which == 1) {
          outb[base + (s >> 5) * 2048 + (d >> 3) * 256 + (s & 31) * 8 + (d & 7)] = val;
        } else {
          outb[base + (s >> 3) * 512 + d * 8 + (s & 7)] = val;
        }
      }
    }
  }
}

// ---------- final GEMM: R6-exact loop, 128x256 tile (2-nbi) ----------
__global__ __launch_bounds__(256) void gemm_out(const u16* __restrict__ A,
                                                const u16* __restrict__ W,
                                                const float* __restrict__ bias,
                                                float* __restrict__ outp) {
  const int K = 512, N = 512;
  __shared__ __align__(16) u16 As[128 * 64];
  __shared__ __align__(16) u16 Bs[256 * 64];
  const int t    = threadIdx.x;
  const int lane = t & 63;
  const int wid  = t >> 6;
  const int g    = lane >> 4, l15 = lane & 15;
  const int wm   = wid >> 1, wn = wid & 1;
  const int wrk  = (blockIdx.x & 7) * 32 + (blockIdx.x >> 3);  // XCD-chunked, 256
  const int mb   = wrk >> 1, nbi = wrk & 1;
  const int m0   = mb << 7, n0 = nbi << 8;
  const int srow = t >> 3;
  const int scol = (((t & 7) ^ (srow & 7)) << 3);
  const int rsw  = l15 & 7;

  f32x4 acc[4][8];
#pragma unroll
  for (int i = 0; i < 4; ++i)
#pragma unroll
    for (int j = 0; j < 8; ++j) acc[i][j] = f32x4{0.f, 0.f, 0.f, 0.f};

  for (int k0 = 0; k0 < K; k0 += 64) {
    SB();
    __builtin_amdgcn_s_barrier();
    SB();
#pragma unroll
    for (int i = 0; i < 4; ++i)
      gload_lds16(A + (size_t)(m0 + i * 32 + srow) * K + k0 + scol, As + i * 2048 + t * 8);
#pragma unroll
    for (int i = 0; i < 8; ++i)
      gload_lds16(W + (size_t)(n0 + i * 32 + srow) * K + k0 + scol, Bs + i * 2048 + t * 8);
    SB();
    asm volatile("s_waitcnt vmcnt(0)" ::: "memory");
    __builtin_amdgcn_s_barrier();
    SB();
#pragma unroll
    for (int kk = 0; kk < 2; ++kk) {
      short8 a[4], b[8];
#pragma unroll
      for (int mi = 0; mi < 4; ++mi)
        a[mi] = *(const short8*)(As + (wm * 64 + mi * 16 + l15) * 64
                                 + (((kk * 4 + g) ^ rsw) << 3));
#pragma unroll
      for (int ni = 0; ni < 8; ++ni)
        b[ni] = *(const short8*)(Bs + (wn * 128 + ni * 16 + l15) * 64
                                 + (((kk * 4 + g) ^ rsw) << 3));
#pragma unroll
      for (int mi = 0; mi < 4; ++mi)
#pragma unroll
        for (int ni = 0; ni < 8; ++ni)
          acc[mi][ni] = __builtin_amdgcn_mfma_f32_16x16x32_bf16(a[mi], b[ni], acc[mi][ni], 0, 0, 0);
    }
  }

#pragma unroll
  for (int ni = 0; ni < 8; ++ni) {
    const int col = n0 + wn * 128 + ni * 16 + l15;
    const float bz = bias[col];
#pragma unroll
    for (int mi = 0; mi < 4; ++mi)
#pragma unroll
      for (int r = 0; r < 4; ++r) {
        const int row = m0 + wm * 64 + mi * 16 + g * 4 + r;
        outp[(size_t)row * N + col] = acc[mi][ni][r] + bz;
      }
  }
}

// ---------- flash attention: wave-pair kv-split + 2-tile ILP (R13) ----------
__global__ __launch_bounds__(256, 2) void attn_kernel(const u16* __restrict__ qh,
                                                      const u16* __restrict__ kh,
                                                      const u16* __restrict__ vT,
                                                      const u64* __restrict__ maskw,
                                                      u16* __restrict__ outc) {
  const int h  = blockIdx.x;
  const int qp = blockIdx.y;
  const int b  = blockIdx.z;
  const int lane = threadIdx.x & 63;
  const int wid  = threadIdx.x >> 6;
  const int pair = wid >> 1, p = wid & 1;
  const int l31 = lane & 31;
  const int hh  = lane >> 5;
  const int hh8 = hh << 3, fourh = hh << 2, eighth = hh << 3;
  const int jt = pair ? (31 - qp) : qp;   // q-tile index 0..31
  const int q0 = jt << 5;
  const int qi = q0 + l31;
  const size_t bh = (size_t)b * 8 + h;
  const u16* Q  = qh + bh * 65536;
  const u16* Kp = kh + bh * 65536;
  const u16* Vt = vT + bh * 65536;
  const u64* mrow = maskw + (size_t)b * 32768 + qi;

  __shared__ float mO[2][32][64];
  __shared__ float mL[2][64];
  __shared__ __align__(16) float Sl[2][32];

  short8 qB[4];
#pragma unroll
  for (int i = 0; i < 4; ++i)
    qB[i] = *(const short8*)(Q + (size_t)qi * 64 + i * 16 + eighth);

  f32x16 O0, O1;
#pragma unroll
  for (int i = 0; i < 16; ++i) { O0[i] = 0.f; O1[i] = 0.f; }
  float lr[4] = {0.f, 0.f, 0.f, 0.f};

  const int nt = jt + 1;

#define LOADK(dst, tt)                                                        \
  { _Pragma("unroll")                                                         \
    for (int i = 0; i < 4; ++i)                                               \
      dst[i] = *(const short8*)(Kp + (tt) * 2048 + ((2 * i + hh) * 32 + l31) * 8); }

#define SOFTMAX(S, wm, pkk)                                                   \
  { const u32 wsh0 = ((u32)(wm)) >> hh8;                                      \
    const u32 wsh1 = ((u32)((wm) >> 32)) >> hh8;                              \
    _Pragma("unroll")                                                         \
    for (int s = 0; s < 4; ++s) {                                             \
      const u32 wsel = (s < 2) ? wsh0 : wsh1;                                 \
      float pv[4];                                                            \
      _Pragma("unroll")                                                       \
      for (int r = 0; r < 4; ++r) {                                           \
        const int m = 4 * s + r;                                              \
        const u32 m2 = (wsel >> (2 * r + 16 * (s & 1))) & 3u;                 \
        float e;                                                              \
        asm("v_exp_f32 %0, %1" : "=v"(e) : "v"((S)[m]));                      \
        const float pp = (m2 != 0u) ? e : 0.f;                                \
        lr[r] += pp;                                                          \
        asm("v_ldexp_f32 %0, %1, %2" : "=v"(pv[r]) : "v"(pp), "v"(m2));       \
      }                                                                       \
      pkk[2 * s]     = cvtpk(pv[0], pv[1]);                                   \
      pkk[2 * s + 1] = cvtpk(pv[2], pv[3]);                                   \
    } }

#define PVSTEP(pkk, tt)                                                       \
  { _Pragma("unroll")                                                         \
    for (int t4 = 0; t4 < 2; ++t4) {                                          \
      u32 a0 = pkk[4 * t4 + 0], b0 = pkk[4 * t4 + 2];                         \
      u32 a1 = pkk[4 * t4 + 1], b1 = pkk[4 * t4 + 3];                         \
      asm("v_permlane32_swap_b32 %0, %1" : "+v"(a0), "+v"(b0));               \
      asm("v_permlane32_swap_b32 %0, %1" : "+v"(a1), "+v"(b1));               \
      u32x4 w; w.x = a0; w.y = a1; w.z = b0; w.w = b1;                        \
      const short8 pa = __builtin_bit_cast(short8, w);                        \
      const short8 v0 = *(const short8*)(Vt + (size_t)((tt) * 4 + t4 * 2 + hh) * 512 + l31 * 8); \
      const short8 v1 = *(const short8*)(Vt + (size_t)((tt) * 4 + t4 * 2 + hh) * 512 + (32 + l31) * 8); \
      O0 = __builtin_amdgcn_mfma_f32_32x32x16_bf16(pa, v0, O0, 0, 0, 0);      \
      O1 = __builtin_amdgcn_mfma_f32_32x32x16_bf16(pa, v1, O1, 0, 0, 0);      \
    } }

  short8 kAa[4], kAb[4];
  LOADK(kAa, p);
  LOADK(kAb, (p + 2));
  u64 wma = mrow[(size_t)p << 10];
  u64 wmb = mrow[(size_t)(p + 2) << 10];

  int t = p;
  while (t < nt) {
    const bool two = (t + 2) < nt;

    f32x16 Sa;
#pragma unroll
    for (int i = 0; i < 16; ++i) Sa[i] = 0.f;
#pragma unroll
    for (int i = 0; i < 4; ++i)
      Sa = __builtin_amdgcn_mfma_f32_32x32x16_bf16(kAa[i], qB[i], Sa, 0, 0, 0);
    f32x16 Sb;
#pragma unroll
    for (int i = 0; i < 16; ++i) Sb[i] = 0.f;
    if (two) {
#pragma unroll
      for (int i = 0; i < 4; ++i)
        Sb = __builtin_amdgcn_mfma_f32_32x32x16_bf16(kAb[i], qB[i], Sb, 0, 0, 0);
    }

    const int tn = t + (two ? 4 : 2);
    u64 wman = 0, wmbn = 0;
    if (tn < nt) {
      LOADK(kAa, tn);
      wman = mrow[(size_t)tn << 10];
      if (tn + 2 < nt) {
        LOADK(kAb, (tn + 2));
        wmbn = mrow[(size_t)(tn + 2) << 10];
      }
    }

    u32 pka[8], pkb[8];
    SOFTMAX(Sa, wma, pka);
    if (two) SOFTMAX(Sb, wmb, pkb);

    PVSTEP(pka, t);
    if (two) PVSTEP(pkb, (t + 2));

    wma = wman; wmb = wmbn;
    t = tn;
  }

#undef LOADK
#undef SOFTMAX
#undef PVSTEP

  float lrun = (lr[0] + lr[1]) + (lr[2] + lr[3]);

  if (p == 1) {
#pragma unroll
    for (int r = 0; r < 16; ++r) {
      mO[pair][r][lane]      = O0[r];
      mO[pair][16 + r][lane] = O1[r];
    }
    mL[pair][lane] = lrun;
  }
  __syncthreads();
  if (p == 0) {
#pragma unroll
    for (int r = 0; r < 16; ++r) {
      O0[r] += mO[pair][r][lane];
      O1[r] += mO[pair][16 + r][lane];
    }
    lrun += mL[pair][lane];

    const float ssum = lrun + __shfl_xor(lrun, 32);
    if (lane < 32) Sl[pair][l31] = (ssum > 0.f) ? 0.25f / ssum : 0.f;
    __builtin_amdgcn_sched_barrier(0);
    asm volatile("s_waitcnt lgkmcnt(0)" ::: "memory");
    __builtin_amdgcn_sched_barrier(0);
#pragma unroll
    for (int t2 = 0; t2 < 4; ++t2) {
      const float4 inv4 = *(const float4*)&Sl[pair][8 * t2 + fourh];
#pragma unroll
      for (int r = 0; r < 4; ++r) {
        const int m = 4 * t2 + r;
        const float iv = (r == 0) ? inv4.x : (r == 1) ? inv4.y : (r == 2) ? inv4.z : inv4.w;
        const int qrow = q0 + 8 * t2 + fourh + r;
        u16* op = outc + ((size_t)b * 1024 + qrow) * 512 + h * 64;
        op[l31]      = f2bf(O0[m] * iv);
        op[32 + l31] = f2bf(O1[m] * iv);
      }
    }
  }
}

// ---------- launch ----------
extern "C" void kernel_launch(void* const* d_in, const int* in_sizes, int n_in,
                              void* d_out, int out_size, void* d_ws, size_t ws_size,
                              hipStream_t stream) {
  (void)in_sizes; (void)n_in; (void)out_size; (void)ws_size;
  const float* q    = (const float*)d_in[0];
  const float* k    = (const float*)d_in[1];
  const float* v    = (const float*)d_in[2];
  const int*  q_seq = (const int*)d_in[3];
  const int*  c_seq = (const int*)d_in[4];
  const float* Wq   = (const float*)d_in[5];
  const float* bq   = (const float*)d_in[6];
  const float* Wk   = (const float*)d_in[7];
  const float* bk   = (const float*)d_in[8];
  const float* Wv   = (const float*)d_in[9];
  const float* bv   = (const float*)d_in[10];
  const float* Wo   = (const float*)d_in[11];
  const float* bo   = (const float*)d_in[12];
  float* out = (float*)d_out;

  char* ws = (char*)d_ws;
  const size_t SZH = 16ull * 8 * 1024 * 64 * 2;   // 16.78 MB per [B][H][...] bf16
  u16* qhb   = (u16*)(ws + 0 * SZH);
  u16* khb   = (u16*)(ws + 1 * SZH);
  u16* vTb   = (u16*)(ws + 2 * SZH);
  u16* attnc = (u16*)(ws + 3 * SZH);
  u16* Wvb = (u16*)(ws + 4 * SZH + 0 * 524288);   // Wcat = [Wv|Wk|Wq] contiguous
  u16* Wkb = (u16*)(ws + 4 * SZH + 1 * 524288);
  u16* Wqb = (u16*)(ws + 4 * SZH + 2 * 524288);
  u16* Wob = (u16*)(ws + 4 * SZH + 3 * 524288);
  int2* meta  = (int2*)(ws + 4 * SZH + 4 * 524288);
  u64* maskw  = (u64*)(ws + 4 * SZH + 4 * 524288 + 131072);

  const int n8w = 512 * 512 / 8;
  cast4_kernel<<<dim3(n8w / 256, 4), 256, 0, stream>>>(Wv, Wk, Wq, Wo,
                                                       Wvb, Wkb, Wqb, Wob, n8w);
  pack_kernel<<<64, 256, 0, stream>>>(q_seq, c_seq, meta, 16384);
  mask_kernel<<<dim3(4, 32, 16), 256, 0, stream>>>(meta, maskw);

  const float KSCALE = 0.18033688011112042f;   // log2(e)/8 -> softmax exp is 2^s
  gemm_qkv<<<dim3(768), 256, 0, stream>>>(q, k, v, Wvb, bv, bk, bq,
                                          qhb, khb, vTb, KSCALE);
  attn_kernel<<<dim3(8, 16, 16), 256, 0, stream>>>(qhb, khb, vTb, maskw, attnc);
  gemm_out<<<dim3(256), 256, 0, stream>>>(attnc, Wob, bo, out);
}

// Round 16
// 136.643 us; speedup vs baseline: 1.4574x; 1.1518x over previous
//
#include <hip/hip_runtime.h>
#include <stdint.h>

typedef unsigned short u16;
typedef unsigned int   u32;
typedef unsigned long long u64;
typedef __attribute__((ext_vector_type(8)))  short short8;   // 8 x bf16 fragment
typedef __attribute__((ext_vector_type(4)))  float f32x4;
typedef __attribute__((ext_vector_type(16))) float f32x16;   // 32x32 MFMA accumulator
typedef __attribute__((ext_vector_type(4)))  unsigned int u32x4;

// ---------- helpers ----------
__device__ __forceinline__ u16 f2bf(float f) {          // RNE f32 -> bf16
  u32 u = __builtin_bit_cast(u32, f);
  u32 r = u + 0x7FFFu + ((u >> 16) & 1u);
  return (u16)(r >> 16);
}

__device__ __forceinline__ u32 cvtpk(float a, float b) { // 2xf32 -> packed bf16
  u32 r;
  asm("v_cvt_pk_bf16_f32 %0, %1, %2" : "=v"(r) : "v"(a), "v"(b));
  return r;
}

// async global->LDS, 16B per lane (dest must be wave-uniform base + lane*16)
__device__ __forceinline__ void gload_lds16(const void* g, void* l) {
  __builtin_amdgcn_global_load_lds(
      (__attribute__((address_space(1))) void*)(uintptr_t)g,
      (__attribute__((address_space(3))) void*)(u32)(uintptr_t)l,
      16, 0, 0);
}

#define SB() __builtin_amdgcn_sched_barrier(0)

// ---------- prep: weight casts (grid.y 0..3) + meta pack (grid.y 4) ----------
__global__ void prep_kernel(const float* __restrict__ s0, const float* __restrict__ s1,
                            const float* __restrict__ s2, const float* __restrict__ s3,
                            u16* __restrict__ d0, u16* __restrict__ d1,
                            u16* __restrict__ d2, u16* __restrict__ d3, int n8,
                            const int* __restrict__ q_seq, const int* __restrict__ c_seq,
                            int2* __restrict__ meta) {
  const int sel = blockIdx.y;
  if (sel < 4) {
    const float* src = sel == 0 ? s0 : sel == 1 ? s1 : sel == 2 ? s2 : s3;
    u16* dst = sel == 0 ? d0 : sel == 1 ? d1 : sel == 2 ? d2 : d3;
    int i = blockIdx.x * blockDim.x + threadIdx.x;
    if (i >= n8) return;
    const float4* s4 = (const float4*)src;
    float4 x = s4[2 * (size_t)i];
    float4 y = s4[2 * (size_t)i + 1];
    u32x4 r;
    r.x = cvtpk(x.x, x.y); r.y = cvtpk(x.z, x.w);
    r.z = cvtpk(y.x, y.y); r.w = cvtpk(y.z, y.w);
    *(u32x4*)(dst + 8 * (size_t)i) = r;
  } else {
    int i = blockIdx.x * blockDim.x + threadIdx.x;
    if (i >= 16384) return;
    u32 bits = 0;
#pragma unroll
    for (int j = 0; j < 32; ++j)
      bits |= (c_seq[(size_t)i * 32 + j] != 0) ? (1u << j) : 0u;
    meta[i] = make_int2(q_seq[i], (int)bits);
  }
}

// ---------- mask precompute: 2-bit m per (b, ktile32, q), tri included ----------
__global__ __launch_bounds__(256) void mask_kernel(const int2* __restrict__ meta,
                                                   u64* __restrict__ maskw) {
  const int qc = blockIdx.x, kt = blockIdx.y, b = blockIdx.z;
  const int t = threadIdx.x;
  const int q = qc * 256 + t;
  __shared__ int2 colm[32];
  if (t < 32) colm[t] = meta[b * 1024 + kt * 32 + t];
  __syncthreads();
  const int2 qm = meta[b * 1024 + q];
  const int rs = qm.x; const u32 rb = (u32)qm.y;
  u64 w = 0;
#pragma unroll
  for (int j = 0; j < 32; ++j) {
    const int2 cm = colm[j];
    const int kj = kt * 32 + j;
    u32 m = 0;
    if (kj < q) m = 1u + (rs == cm.x ? 1u : 0u) + (((rb & (u32)cm.y) != 0u) ? 1u : 0u);
    w |= (u64)m << (2 * j);
  }
  maskw[((size_t)b * 32 + kt) * 1024 + q] = w;
}

// ---------- fused QKV projection GEMM (R6/R13-exact, best measured 73us) ----
// grid.y = sel: 0->qh, 1->kh, 2->vT. T2 XOR-swizzled LDS via pre-swizzled
// SOURCE col (rule #21) + A f32 reg-prefetch one K-step ahead, vmcnt(8).
// XCD swizzle: w=(x&7)*64+(x>>3).
//  sel 0 (Q): [b][h][s][64]
//  sel 1 (K): tiled [b][h][s/32][d/8][s&31][d&7]  (attn reads 1KB contig)
//  sel 2 (V): tiled [b][h][s/8][d][s&7]           (attn reads 2x512B contig)
__global__ __launch_bounds__(256) void gemm_qkv(const float* __restrict__ qf,
                                                const float* __restrict__ kf,
                                                const float* __restrict__ vf,
                                                const u16* __restrict__ Wvb,
                                                const u16* __restrict__ Wkb,
                                                const u16* __restrict__ Wqb,
                                                const float* __restrict__ bv,
                                                const float* __restrict__ bk,
                                                const float* __restrict__ bq,
                                                u16* __restrict__ qhb,
                                                u16* __restrict__ khb,
                                                u16* __restrict__ vTb,
                                                float kscale) {
  const int sel = blockIdx.y;
  const float* Af   = sel == 0 ? qf : sel == 1 ? kf : vf;
  const u16*   W    = sel == 0 ? Wvb : sel == 1 ? Wkb : Wqb;   // ref weight shuffle
  const float* bias = sel == 0 ? bv : sel == 1 ? bk : bq;
  const float scale = sel == 1 ? kscale : 1.0f;
  const int K = 512;

  __shared__ __align__(16) u16 As[128 * 64];
  __shared__ __align__(16) u16 Bs[128 * 64];
  const int t    = threadIdx.x;
  const int lane = t & 63;
  const int wid  = t >> 6;
  const int g    = lane >> 4, l15 = lane & 15;
  const int wm   = wid >> 1, wn = wid & 1;
  const int wrk  = (blockIdx.x & 7) * 64 + (blockIdx.x >> 3);  // XCD-chunked
  const int mb   = wrk >> 2, nbi = wrk & 3;
  const int m0   = mb << 7, n0 = nbi << 7;
  const int srow = t >> 3;
  const int scol = (((t & 7) ^ (srow & 7)) << 3);   // pre-swizzled source slot
  const int dcol = ((t & 7) << 3);                  // linear LDS dest slot
  const int rsw  = l15 & 7;                         // read-side swizzle key

  f32x4 acc[4][4];
#pragma unroll
  for (int i = 0; i < 4; ++i)
#pragma unroll
    for (int j = 0; j < 4; ++j) acc[i][j] = f32x4{0.f, 0.f, 0.f, 0.f};

  // prologue: A(k0=0) into regs
  float4 ax[4], ay[4];
#pragma unroll
  for (int i = 0; i < 4; ++i) {
    const float* src = Af + (size_t)(m0 + 32 * i + srow) * K + scol;
    ax[i] = *(const float4*)src;
    ay[i] = *(const float4*)(src + 4);
  }

  for (int k0 = 0; k0 < K; k0 += 64) {
    SB();
    __builtin_amdgcn_s_barrier();      // prev-iter LDS reads done
    SB();
    // B stage (4 gload_lds, linear dest, pre-swizzled source)
#pragma unroll
    for (int i = 0; i < 4; ++i)
      gload_lds16(W + (size_t)(n0 + i * 32 + srow) * K + k0 + scol,
                  Bs + i * 2048 + t * 8);
    // A cvt (regs loaded last iter) -> linear ds_write
#pragma unroll
    for (int i = 0; i < 4; ++i) {
      u32x4 r;
      r.x = cvtpk(ax[i].x, ax[i].y); r.y = cvtpk(ax[i].z, ax[i].w);
      r.z = cvtpk(ay[i].x, ay[i].y); r.w = cvtpk(ay[i].z, ay[i].w);
      *(u32x4*)(As + (32 * i + srow) * 64 + dcol) = r;
    }
    SB();
    // A prefetch next K-step (wrap keeps 8 loads every iter -> vmcnt invariant)
    const int kn = (k0 + 64) & (K - 1);
#pragma unroll
    for (int i = 0; i < 4; ++i) {
      const float* src = Af + (size_t)(m0 + 32 * i + srow) * K + kn + scol;
      ax[i] = *(const float4*)src;
      ay[i] = *(const float4*)(src + 4);
    }
    SB();
    asm volatile("s_waitcnt vmcnt(8) lgkmcnt(0)" ::: "memory");  // B+dsW done; A flies
    __builtin_amdgcn_s_barrier();
    SB();
#pragma unroll
    for (int kk = 0; kk < 2; ++kk) {
      short8 a[4], b[4];
#pragma unroll
      for (int mi = 0; mi < 4; ++mi)
        a[mi] = *(const short8*)(As + (wm * 64 + mi * 16 + l15) * 64
                                 + (((kk * 4 + g) ^ rsw) << 3));
#pragma unroll
      for (int ni = 0; ni < 4; ++ni)
        b[ni] = *(const short8*)(Bs + (wn * 64 + ni * 16 + l15) * 64
                                 + (((kk * 4 + g) ^ rsw) << 3));
#pragma unroll
      for (int mi = 0; mi < 4; ++mi)
#pragma unroll
        for (int ni = 0; ni < 4; ++ni)
          acc[mi][ni] = __builtin_amdgcn_mfma_f32_16x16x32_bf16(a[mi], b[ni], acc[mi][ni], 0, 0, 0);
    }
  }
  asm volatile("s_waitcnt vmcnt(0)" ::: "memory");   // drain dead last prefetch

#pragma unroll
  for (int ni = 0; ni < 4; ++ni) {
    const int col = n0 + wn * 64 + ni * 16 + l15;
    const float bz = bias[col];
#pragma unroll
    for (int mi = 0; mi < 4; ++mi) {
#pragma unroll
      for (int r = 0; r < 4; ++r) {
        const int row = m0 + wm * 64 + mi * 16 + g * 4 + r;
        const u16 val = f2bf((acc[mi][ni][r] + bz) * scale);
        const size_t base = ((size_t)(row >> 10) * 8 + (col >> 6)) * 65536;
        const int s = row & 1023, d = col & 63;
        if (sel == 0) {
          qhb[base + (size_t)s * 64 + d] = val;
        } else if (sel == 1) {
          khb[base + (s >> 5) * 2048 + (d >> 3) * 256 + (s & 31) * 8 + (d & 7)] = val;
        } else {
          vTb[base + (s >> 3) * 512 + d * 8 + (s & 7)] = val;
        }
      }
    }
  }
}

// ---------- final GEMM: out = attnc @ Wo^T + bo (R6/R13-exact) ----------
__global__ __launch_bounds__(256) void gemm_out(const u16* __restrict__ A,
                                                const u16* __restrict__ W,
                                                const float* __restrict__ bias,
                                                float* __restrict__ outp) {
  const int K = 512, N = 512;
  __shared__ __align__(16) u16 As[128 * 64];
  __shared__ __align__(16) u16 Bs[128 * 64];
  const int t    = threadIdx.x;
  const int lane = t & 63;
  const int wid  = t >> 6;
  const int g    = lane >> 4, l15 = lane & 15;
  const int wm   = wid >> 1, wn = wid & 1;
  const int wrk  = (blockIdx.x & 7) * 64 + (blockIdx.x >> 3);  // XCD-chunked
  const int mb   = wrk >> 2, nbi = wrk & 3;
  const int m0   = mb << 7, n0 = nbi << 7;
  const int srow = t >> 3;
  const int scol = (((t & 7) ^ (srow & 7)) << 3);
  const int rsw  = l15 & 7;

  f32x4 acc[4][4];
#pragma unroll
  for (int i = 0; i < 4; ++i)
#pragma unroll
    for (int j = 0; j < 4; ++j) acc[i][j] = f32x4{0.f, 0.f, 0.f, 0.f};

  for (int k0 = 0; k0 < K; k0 += 64) {
    SB();
    __builtin_amdgcn_s_barrier();
    SB();
#pragma unroll
    for (int i = 0; i < 4; ++i) {
      gload_lds16(A + (size_t)(m0 + i * 32 + srow) * K + k0 + scol, As + i * 2048 + t * 8);
      gload_lds16(W + (size_t)(n0 + i * 32 + srow) * K + k0 + scol, Bs + i * 2048 + t * 8);
    }
    SB();
    asm volatile("s_waitcnt vmcnt(0)" ::: "memory");
    __builtin_amdgcn_s_barrier();
    SB();
#pragma unroll
    for (int kk = 0; kk < 2; ++kk) {
      short8 a[4], b[4];
#pragma unroll
      for (int mi = 0; mi < 4; ++mi)
        a[mi] = *(const short8*)(As + (wm * 64 + mi * 16 + l15) * 64
                                 + (((kk * 4 + g) ^ rsw) << 3));
#pragma unroll
      for (int ni = 0; ni < 4; ++ni)
        b[ni] = *(const short8*)(Bs + (wn * 64 + ni * 16 + l15) * 64
                                 + (((kk * 4 + g) ^ rsw) << 3));
#pragma unroll
      for (int mi = 0; mi < 4; ++mi)
#pragma unroll
        for (int ni = 0; ni < 4; ++ni)
          acc[mi][ni] = __builtin_amdgcn_mfma_f32_16x16x32_bf16(a[mi], b[ni], acc[mi][ni], 0, 0, 0);
    }
  }

#pragma unroll
  for (int ni = 0; ni < 4; ++ni) {
    const int col = n0 + wn * 64 + ni * 16 + l15;
    const float bz = bias[col];
#pragma unroll
    for (int mi = 0; mi < 4; ++mi)
#pragma unroll
      for (int r = 0; r < 4; ++r) {
        const int row = m0 + wm * 64 + mi * 16 + g * 4 + r;
        outp[(size_t)row * N + col] = acc[mi][ni][r] + bz;
      }
  }
}

// ---------- flash attention: wave-pair kv-split + 2-tile ILP (R13-exact) ----
__global__ __launch_bounds__(256, 2) void attn_kernel(const u16* __restrict__ qh,
                                                      const u16* __restrict__ kh,
                                                      const u16* __restrict__ vT,
                                                      const u64* __restrict__ maskw,
                                                      u16* __restrict__ outc) {
  const int h  = blockIdx.x;
  const int qp = blockIdx.y;
  const int b  = blockIdx.z;
  const int lane = threadIdx.x & 63;
  const int wid  = threadIdx.x >> 6;
  const int pair = wid >> 1, p = wid & 1;
  const int l31 = lane & 31;
  const int hh  = lane >> 5;
  const int hh8 = hh << 3, fourh = hh << 2, eighth = hh << 3;
  const int jt = pair ? (31 - qp) : qp;   // q-tile index 0..31
  const int q0 = jt << 5;
  const int qi = q0 + l31;
  const size_t bh = (size_t)b * 8 + h;
  const u16* Q  = qh + bh * 65536;
  const u16* Kp = kh + bh * 65536;
  const u16* Vt = vT + bh * 65536;
  const u64* mrow = maskw + (size_t)b * 32768 + qi;

  __shared__ float mO[2][32][64];
  __shared__ float mL[2][64];
  __shared__ __align__(16) float Sl[2][32];

  short8 qB[4];
#pragma unroll
  for (int i = 0; i < 4; ++i)
    qB[i] = *(const short8*)(Q + (size_t)qi * 64 + i * 16 + eighth);

  f32x16 O0, O1;
#pragma unroll
  for (int i = 0; i < 16; ++i) { O0[i] = 0.f; O1[i] = 0.f; }
  float lr[4] = {0.f, 0.f, 0.f, 0.f};

  const int nt = jt + 1;

#define LOADK(dst, tt)                                                        \
  { _Pragma("unroll")                                                         \
    for (int i = 0; i < 4; ++i)                                               \
      dst[i] = *(const short8*)(Kp + (tt) * 2048 + ((2 * i + hh) * 32 + l31) * 8); }

#define SOFTMAX(S, wm, pkk)                                                   \
  { const u32 wsh0 = ((u32)(wm)) >> hh8;                                      \
    const u32 wsh1 = ((u32)((wm) >> 32)) >> hh8;                              \
    _Pragma("unroll")                                                         \
    for (int s = 0; s < 4; ++s) {                                             \
      const u32 wsel = (s < 2) ? wsh0 : wsh1;                                 \
      float pv[4];                                                            \
      _Pragma("unroll")                                                       \
      for (int r = 0; r < 4; ++r) {                                           \
        const int m = 4 * s + r;                                              \
        const u32 m2 = (wsel >> (2 * r + 16 * (s & 1))) & 3u;                 \
        float e;                                                              \
        asm("v_exp_f32 %0, %1" : "=v"(e) : "v"((S)[m]));                      \
        const float pp = (m2 != 0u) ? e : 0.f;                                \
        lr[r] += pp;                                                          \
        asm("v_ldexp_f32 %0, %1, %2" : "=v"(pv[r]) : "v"(pp), "v"(m2));       \
      }                                                                       \
      pkk[2 * s]     = cvtpk(pv[0], pv[1]);                                   \
      pkk[2 * s + 1] = cvtpk(pv[2], pv[3]);                                   \
    } }

#define PVSTEP(pkk, tt)                                                       \
  { _Pragma("unroll")                                                         \
    for (int t4 = 0; t4 < 2; ++t4) {                                          \
      u32 a0 = pkk[4 * t4 + 0], b0 = pkk[4 * t4 + 2];                         \
      u32 a1 = pkk[4 * t4 + 1], b1 = pkk[4 * t4 + 3];                         \
      asm("v_permlane32_swap_b32 %0, %1" : "+v"(a0), "+v"(b0));               \
      asm("v_permlane32_swap_b32 %0, %1" : "+v"(a1), "+v"(b1));               \
      u32x4 w; w.x = a0; w.y = a1; w.z = b0; w.w = b1;                        \
      const short8 pa = __builtin_bit_cast(short8, w);                        \
      const short8 v0 = *(const short8*)(Vt + (size_t)((tt) * 4 + t4 * 2 + hh) * 512 + l31 * 8); \
      const short8 v1 = *(const short8*)(Vt + (size_t)((tt) * 4 + t4 * 2 + hh) * 512 + (32 + l31) * 8); \
      O0 = __builtin_amdgcn_mfma_f32_32x32x16_bf16(pa, v0, O0, 0, 0, 0);      \
      O1 = __builtin_amdgcn_mfma_f32_32x32x16_bf16(pa, v1, O1, 0, 0, 0);      \
    } }

  short8 kAa[4], kAb[4];
  LOADK(kAa, p);
  LOADK(kAb, (p + 2));
  u64 wma = mrow[(size_t)p << 10];
  u64 wmb = mrow[(size_t)(p + 2) << 10];

  int t = p;
  while (t < nt) {
    const bool two = (t + 2) < nt;

    f32x16 Sa;
#pragma unroll
    for (int i = 0; i < 16; ++i) Sa[i] = 0.f;
#pragma unroll
    for (int i = 0; i < 4; ++i)
      Sa = __builtin_amdgcn_mfma_f32_32x32x16_bf16(kAa[i], qB[i], Sa, 0, 0, 0);
    f32x16 Sb;
#pragma unroll
    for (int i = 0; i < 16; ++i) Sb[i] = 0.f;
    if (two) {
#pragma unroll
      for (int i = 0; i < 4; ++i)
        Sb = __builtin_amdgcn_mfma_f32_32x32x16_bf16(kAb[i], qB[i], Sb, 0, 0, 0);
    }

    const int tn = t + (two ? 4 : 2);
    u64 wman = 0, wmbn = 0;
    if (tn < nt) {
      LOADK(kAa, tn);
      wman = mrow[(size_t)tn << 10];
      if (tn + 2 < nt) {
        LOADK(kAb, (tn + 2));
        wmbn = mrow[(size_t)(tn + 2) << 10];
      }
    }

    u32 pka[8], pkb[8];
    SOFTMAX(Sa, wma, pka);
    if (two) SOFTMAX(Sb, wmb, pkb);

    PVSTEP(pka, t);
    if (two) PVSTEP(pkb, (t + 2));

    wma = wman; wmb = wmbn;
    t = tn;
  }

#undef LOADK
#undef SOFTMAX
#undef PVSTEP

  float lrun = (lr[0] + lr[1]) + (lr[2] + lr[3]);

  if (p == 1) {
#pragma unroll
    for (int r = 0; r < 16; ++r) {
      mO[pair][r][lane]      = O0[r];
      mO[pair][16 + r][lane] = O1[r];
    }
    mL[pair][lane] = lrun;
  }
  __syncthreads();
  if (p == 0) {
#pragma unroll
    for (int r = 0; r < 16; ++r) {
      O0[r] += mO[pair][r][lane];
      O1[r] += mO[pair][16 + r][lane];
    }
    lrun += mL[pair][lane];

    const float ssum = lrun + __shfl_xor(lrun, 32);
    if (lane < 32) Sl[pair][l31] = (ssum > 0.f) ? 0.25f / ssum : 0.f;
    __builtin_amdgcn_sched_barrier(0);
    asm volatile("s_waitcnt lgkmcnt(0)" ::: "memory");
    __builtin_amdgcn_sched_barrier(0);
#pragma unroll
    for (int t2 = 0; t2 < 4; ++t2) {
      const float4 inv4 = *(const float4*)&Sl[pair][8 * t2 + fourh];
#pragma unroll
      for (int r = 0; r < 4; ++r) {
        const int m = 4 * t2 + r;
        const float iv = (r == 0) ? inv4.x : (r == 1) ? inv4.y : (r == 2) ? inv4.z : inv4.w;
        const int qrow = q0 + 8 * t2 + fourh + r;
        u16* op = outc + ((size_t)b * 1024 + qrow) * 512 + h * 64;
        op[l31]      = f2bf(O0[m] * iv);
        op[32 + l31] = f2bf(O1[m] * iv);
      }
    }
  }
}

// ---------- launch ----------
extern "C" void kernel_launch(void* const* d_in, const int* in_sizes, int n_in,
                              void* d_out, int out_size, void* d_ws, size_t ws_size,
                              hipStream_t stream) {
  (void)in_sizes; (void)n_in; (void)out_size; (void)ws_size;
  const float* q    = (const float*)d_in[0];
  const float* k    = (const float*)d_in[1];
  const float* v    = (const float*)d_in[2];
  const int*  q_seq = (const int*)d_in[3];
  const int*  c_seq = (const int*)d_in[4];
  const float* Wq   = (const float*)d_in[5];
  const float* bq   = (const float*)d_in[6];
  const float* Wk   = (const float*)d_in[7];
  const float* bk   = (const float*)d_in[8];
  const float* Wv   = (const float*)d_in[9];
  const float* bv   = (const float*)d_in[10];
  const float* Wo   = (const float*)d_in[11];
  const float* bo   = (const float*)d_in[12];
  float* out = (float*)d_out;

  char* ws = (char*)d_ws;
  const size_t SZH = 16ull * 8 * 1024 * 64 * 2;   // 16.78 MB per [B][H][...] bf16
  u16* qhb   = (u16*)(ws + 0 * SZH);
  u16* khb   = (u16*)(ws + 1 * SZH);
  u16* vTb   = (u16*)(ws + 2 * SZH);
  u16* attnc = (u16*)(ws + 3 * SZH);
  u16* Wvb = (u16*)(ws + 4 * SZH + 0 * 524288);
  u16* Wkb = (u16*)(ws + 4 * SZH + 1 * 524288);
  u16* Wqb = (u16*)(ws + 4 * SZH + 2 * 524288);
  u16* Wob = (u16*)(ws + 4 * SZH + 3 * 524288);
  int2* meta  = (int2*)(ws + 4 * SZH + 4 * 524288);
  u64* maskw  = (u64*)(ws + 4 * SZH + 4 * 524288 + 131072);

  const int n8w = 512 * 512 / 8;   // 32768 -> 128 blocks of 256
  prep_kernel<<<dim3(128, 5), 256, 0, stream>>>(Wv, Wk, Wq, Wo,
                                                Wvb, Wkb, Wqb, Wob, n8w,
                                                q_seq, c_seq, meta);
  mask_kernel<<<dim3(4, 32, 16), 256, 0, stream>>>(meta, maskw);

  const float KSCALE = 0.18033688011112042f;   // log2(e)/8 -> softmax exp is 2^s
  gemm_qkv<<<dim3(512, 3), 256, 0, stream>>>(q, k, v, Wvb, Wkb, Wqb,
                                             bv, bk, bq, qhb, khb, vTb, KSCALE);
  attn_kernel<<<dim3(8, 16, 16), 256, 0, stream>>>(qhb, khb, vTb, maskw, attnc);
  gemm_out<<<512, 256, 0, stream>>>(attnc, Wob, bo, out);
}